// Round 1
// baseline (1212.780 us; speedup 1.0000x reference)
//
#include <hip/hip_runtime.h>
#include <hip/hip_bf16.h>

// Problem constants (match reference)
#define NNODES 50000
#define PADM   50048          // 128 * 391, multiple of BM and of 4
#define CDIM   128

// ---------------- CSR build ----------------

__global__ void k_zero_cnt(int* __restrict__ cnt, int n) {
    int i = blockIdx.x * 256 + threadIdx.x;
    if (i < n) cnt[i] = 0;
}

__global__ void k_count(const int* __restrict__ dst, int E, int* __restrict__ cnt) {
    int e = blockIdx.x * 256 + threadIdx.x;
    if (e < E) atomicAdd(&cnt[dst[e]], 1);
}

__global__ void k_dinv(const int* __restrict__ cnt, float* __restrict__ dinv, int n) {
    int i = blockIdx.x * 256 + threadIdx.x;
    if (i < n) dinv[i] = rsqrtf((float)(cnt[i] + 1));   // +1 self loop
}

// single-block exclusive scan of cnt[0..n) -> offs[0..n], cursor copy
__global__ __launch_bounds__(1024) void k_scan(const int* __restrict__ cnt, int n,
                                               int* __restrict__ offs, int* __restrict__ cursor) {
    __shared__ int sums[1024];
    int t = threadIdx.x;
    int per = (n + 1023) / 1024;
    int start = t * per;
    int end = start + per; if (end > n) end = n;
    int s = 0;
    for (int i = start; i < end && i >= 0; ++i) s += cnt[i];
    sums[t] = s;
    __syncthreads();
    for (int d = 1; d < 1024; d <<= 1) {
        int v = (t >= d) ? sums[t - d] : 0;
        __syncthreads();
        sums[t] += v;
        __syncthreads();
    }
    int base = (t == 0) ? 0 : sums[t - 1];
    for (int i = start; i < end; ++i) {
        offs[i] = base; cursor[i] = base;
        base += cnt[i];
    }
    if (t == 1023) offs[n] = sums[1023];
}

__global__ void k_fill(const int* __restrict__ src, const int* __restrict__ dst, int E,
                       int* __restrict__ cursor, const float* __restrict__ dinv,
                       int* __restrict__ csr_src, float* __restrict__ csr_w) {
    int e = blockIdx.x * 256 + threadIdx.x;
    if (e < E) {
        int s = src[e], d = dst[e];
        int slot = atomicAdd(&cursor[d], 1);
        csr_src[slot] = s;
        csr_w[slot] = dinv[s] * dinv[d];
    }
}

// ---------------- aggregation: one wave per node ----------------

template <int V> struct VecT;
template <> struct VecT<2> { using T = float2; };
template <> struct VecT<4> { using T = float4; };

template <int C>
__global__ __launch_bounds__(256) void k_aggregate(
    const float* __restrict__ x,       // [>=NNODES][C]
    const int* __restrict__ offs,      // [NNODES+1]
    const int* __restrict__ csr_src,
    const float* __restrict__ csr_w,
    const float* __restrict__ dinv,
    float* __restrict__ out,           // [PADM][C], pad rows zeroed here
    int nvalid, int padm)
{
    constexpr int V = C / 64;
    using VT = typename VecT<V>::T;
    int wave = threadIdx.x >> 6;
    int lane = threadIdx.x & 63;
    int node = blockIdx.x * 4 + wave;
    if (node >= padm) return;

    float acc[V];
#pragma unroll
    for (int v = 0; v < V; ++v) acc[v] = 0.f;

    if (node < nvalid) {
        float di = dinv[node];
        float w0 = di * di;
        VT xv = *(const VT*)(x + (size_t)node * C + lane * V);
        const float* xp = (const float*)&xv;
#pragma unroll
        for (int v = 0; v < V; ++v) acc[v] = w0 * xp[v];
        int j0 = offs[node], j1 = offs[node + 1];
        for (int j = j0; j < j1; ++j) {
            int s = csr_src[j];
            float w = csr_w[j];
            VT sv = *(const VT*)(x + (size_t)s * C + lane * V);
            const float* sp = (const float*)&sv;
#pragma unroll
            for (int v = 0; v < V; ++v) acc[v] = fmaf(w, sp[v], acc[v]);
        }
    }
    VT ov;
    float* op = (float*)&ov;
#pragma unroll
    for (int v = 0; v < V; ++v) op[v] = acc[v];
    *(VT*)(out + (size_t)node * C + lane * V) = ov;
}

// ---------------- fp32 GEMM: C = A[M][K] * W[N][K]^T + b, optional ReLU ----------------

#define BM 128
#define BN 128
#define BK 16

template <bool RELU>
__global__ __launch_bounds__(256) void k_gemm(
    const float* __restrict__ A,   // [M][K], M multiple of 128, pad rows zero
    const float* __restrict__ W,   // [N][K]
    const float* __restrict__ b,   // [N]
    float* __restrict__ C,         // [Mvalid or M][N]
    int M, int N, int K, int Mvalid)
{
    __shared__ float As[BK][BM];
    __shared__ float Bs[BK][BN];
    int tid = threadIdx.x;
    int bm0 = blockIdx.x * BM;
    int bn0 = blockIdx.y * BN;
    int tm0 = (tid >> 4) * 8;
    int tn0 = (tid & 15) * 8;
    int lr = tid >> 2;          // 0..63
    int lc = (tid & 3) * 4;     // 0,4,8,12

    float acc[8][8];
#pragma unroll
    for (int i = 0; i < 8; ++i)
#pragma unroll
        for (int j = 0; j < 8; ++j) acc[i][j] = 0.f;

    for (int k0 = 0; k0 < K; k0 += BK) {
#pragma unroll
        for (int h = 0; h < 2; ++h) {
            int r = lr + h * 64;
            float4 v = *(const float4*)&A[(size_t)(bm0 + r) * K + k0 + lc];
            As[lc + 0][r] = v.x; As[lc + 1][r] = v.y;
            As[lc + 2][r] = v.z; As[lc + 3][r] = v.w;
        }
#pragma unroll
        for (int h = 0; h < 2; ++h) {
            int r = lr + h * 64;
            float4 v = *(const float4*)&W[(size_t)(bn0 + r) * K + k0 + lc];
            Bs[lc + 0][r] = v.x; Bs[lc + 1][r] = v.y;
            Bs[lc + 2][r] = v.z; Bs[lc + 3][r] = v.w;
        }
        __syncthreads();
#pragma unroll
        for (int kk = 0; kk < BK; ++kk) {
            float4 a0 = *(const float4*)&As[kk][tm0];
            float4 a1 = *(const float4*)&As[kk][tm0 + 4];
            float4 b0 = *(const float4*)&Bs[kk][tn0];
            float4 b1 = *(const float4*)&Bs[kk][tn0 + 4];
            float am[8] = {a0.x, a0.y, a0.z, a0.w, a1.x, a1.y, a1.z, a1.w};
            float bn[8] = {b0.x, b0.y, b0.z, b0.w, b1.x, b1.y, b1.z, b1.w};
#pragma unroll
            for (int i = 0; i < 8; ++i)
#pragma unroll
                for (int j = 0; j < 8; ++j)
                    acc[i][j] = fmaf(am[i], bn[j], acc[i][j]);
        }
        __syncthreads();
    }

    float4 bias0 = *(const float4*)&b[bn0 + tn0];
    float4 bias1 = *(const float4*)&b[bn0 + tn0 + 4];
    const float bb[8] = {bias0.x, bias0.y, bias0.z, bias0.w,
                         bias1.x, bias1.y, bias1.z, bias1.w};
#pragma unroll
    for (int i = 0; i < 8; ++i) {
        int row = bm0 + tm0 + i;
        if (row < Mvalid) {
            float4 o0, o1;
            float* o0p = (float*)&o0; float* o1p = (float*)&o1;
#pragma unroll
            for (int j = 0; j < 4; ++j) {
                float v = acc[i][j] + bb[j];
                if (RELU) v = fmaxf(v, 0.f);
                o0p[j] = v;
            }
#pragma unroll
            for (int j = 0; j < 4; ++j) {
                float v = acc[i][4 + j] + bb[4 + j];
                if (RELU) v = fmaxf(v, 0.f);
                o1p[j] = v;
            }
            *(float4*)&C[(size_t)row * N + bn0 + tn0] = o0;
            *(float4*)&C[(size_t)row * N + bn0 + tn0 + 4] = o1;
        }
    }
}

// ---------------- launch ----------------

static inline size_t align_up(size_t x, size_t a) { return (x + a - 1) & ~(a - 1); }

extern "C" void kernel_launch(void* const* d_in, const int* in_sizes, int n_in,
                              void* d_out, int out_size, void* d_ws, size_t ws_size,
                              hipStream_t stream) {
    const int*   edge_index = (const int*)d_in[0];    // [2][E]
    const float* node = (const float*)d_in[1];        // [NNODES][128]
    const float* W1 = (const float*)d_in[2];
    const float* b1 = (const float*)d_in[3];
    const float* W2 = (const float*)d_in[4];
    const float* b2 = (const float*)d_in[5];
    const float* W3 = (const float*)d_in[6];
    const float* b3 = (const float*)d_in[7];
    const float* Wfc = (const float*)d_in[8];
    const float* bfc = (const float*)d_in[9];
    float* out = (float*)d_out;

    const int E = in_sizes[0] / 2;   // 400000
    const int NV = NNODES;
    const int P = PADM;

    // workspace layout
    char* ws = (char*)d_ws;
    size_t off = 0;
    int* cnt = (int*)(ws + off);          off = align_up(off + (size_t)NV * 4, 1024);
    int* offs = (int*)(ws + off);         off = align_up(off + (size_t)(NV + 1) * 4, 1024);
    int* cursor = (int*)(ws + off);       off = align_up(off + (size_t)NV * 4, 1024);
    float* dinv = (float*)(ws + off);     off = align_up(off + (size_t)NV * 4, 1024);
    int* csr_src = (int*)(ws + off);      off = align_up(off + (size_t)E * 4, 1024);
    float* csr_w = (float*)(ws + off);    off = align_up(off + (size_t)E * 4, 1024);
    float* agg = (float*)(ws + off);      off = align_up(off + (size_t)P * 256 * 4, 1024);
    float* xbuf = (float*)(ws + off);     off = align_up(off + (size_t)P * 512 * 4, 1024);

    const int* src = edge_index;
    const int* dst = edge_index + E;

    // CSR build
    k_zero_cnt<<<(NV + 255) / 256, 256, 0, stream>>>(cnt, NV);
    k_count<<<(E + 255) / 256, 256, 0, stream>>>(dst, E, cnt);
    k_dinv<<<(NV + 255) / 256, 256, 0, stream>>>(cnt, dinv, NV);
    k_scan<<<1, 1024, 0, stream>>>(cnt, NV, offs, cursor);
    k_fill<<<(E + 255) / 256, 256, 0, stream>>>(src, dst, E, cursor, dinv, csr_src, csr_w);

    dim3 blk(256);
    int aggGrid = P / 4;

    // layer 1: aggregate(node) -> agg[128], gemm -> xbuf[128]
    k_aggregate<128><<<aggGrid, blk, 0, stream>>>(node, offs, csr_src, csr_w, dinv, agg, NV, P);
    k_gemm<true><<<dim3(P / BM, 128 / BN), blk, 0, stream>>>(agg, W1, b1, xbuf, P, 128, 128, P);

    // layer 2: aggregate(x1) -> agg[128], gemm -> xbuf[256]
    k_aggregate<128><<<aggGrid, blk, 0, stream>>>(xbuf, offs, csr_src, csr_w, dinv, agg, NV, P);
    k_gemm<true><<<dim3(P / BM, 256 / BN), blk, 0, stream>>>(agg, W2, b2, xbuf, P, 256, 128, P);

    // layer 3: aggregate(x2) -> agg[256], gemm -> xbuf[512]
    k_aggregate<256><<<aggGrid, blk, 0, stream>>>(xbuf, offs, csr_src, csr_w, dinv, agg, NV, P);
    k_gemm<true><<<dim3(P / BM, 512 / BN), blk, 0, stream>>>(agg, W3, b3, xbuf, P, 512, 256, P);

    // FC: out = x3 @ Wfc^T + bfc  (no relu), store only valid rows
    k_gemm<false><<<dim3(P / BM, 1024 / BN), blk, 0, stream>>>(xbuf, Wfc, bfc, out, P, 1024, 512, NV);
}

// Round 2
// 663.149 us; speedup vs baseline: 1.8288x; 1.8288x over previous
//
#include <hip/hip_runtime.h>
#include <hip/hip_bf16.h>

typedef unsigned short u16;
typedef unsigned int   u32;
typedef unsigned long long u64;
typedef __attribute__((ext_vector_type(8))) short bf16x8;
typedef __attribute__((ext_vector_type(4))) float f32x4;

#define NNODES 50000
#define PADM   50048          // 128 * 391

#define GAS __attribute__((address_space(1)))
#define LAS __attribute__((address_space(3)))

__device__ __forceinline__ u16 f32_bf16_rne(float x) {
    u32 u = __float_as_uint(x);
    return (u16)((u + 0x7fffu + ((u >> 16) & 1u)) >> 16);
}
__device__ __forceinline__ float bf16_f32(u16 h) {
    return __uint_as_float(((u32)h) << 16);
}

// ---------------- CSR build ----------------

__global__ void k_zero_cnt(int* __restrict__ cnt, int n) {
    int i = blockIdx.x * 256 + threadIdx.x;
    if (i < n) cnt[i] = 0;
}

__global__ void k_count(const int* __restrict__ dst, int E, int* __restrict__ cnt) {
    int e = blockIdx.x * 256 + threadIdx.x;
    if (e < E) atomicAdd(&cnt[dst[e]], 1);
}

__global__ void k_dinv(const int* __restrict__ cnt, float* __restrict__ dinv, int n) {
    int i = blockIdx.x * 256 + threadIdx.x;
    if (i < n) dinv[i] = rsqrtf((float)(cnt[i] + 1));   // +1 self loop
}

__global__ __launch_bounds__(1024) void k_scan(const int* __restrict__ cnt, int n,
                                               int* __restrict__ offs, int* __restrict__ cursor) {
    __shared__ int sums[1024];
    int t = threadIdx.x;
    int per = (n + 1023) / 1024;
    int start = t * per;
    int end = start + per; if (end > n) end = n;
    int s = 0;
    for (int i = start; i < end; ++i) s += cnt[i];
    sums[t] = s;
    __syncthreads();
    for (int d = 1; d < 1024; d <<= 1) {
        int v = (t >= d) ? sums[t - d] : 0;
        __syncthreads();
        sums[t] += v;
        __syncthreads();
    }
    int base = (t == 0) ? 0 : sums[t - 1];
    for (int i = start; i < end; ++i) {
        offs[i] = base; cursor[i] = base;
        base += cnt[i];
    }
    if (t == 1023) offs[n] = sums[1023];
}

__global__ void k_fill(const int* __restrict__ src, const int* __restrict__ dst, int E,
                       int* __restrict__ cursor, const float* __restrict__ dinv,
                       int* __restrict__ csr_src, float* __restrict__ csr_w) {
    int e = blockIdx.x * 256 + threadIdx.x;
    if (e < E) {
        int s = src[e], d = dst[e];
        int slot = atomicAdd(&cursor[d], 1);
        csr_src[slot] = s;
        csr_w[slot] = dinv[s] * dinv[d];
    }
}

// ---------------- weight split: W[N][K] f32 -> [N][2K] bf16 [hi|lo] ----------------

__global__ void k_splitW(const float* __restrict__ W, u16* __restrict__ W2, int total, int K) {
    int i = blockIdx.x * 256 + threadIdx.x;
    if (i >= total) return;
    int n = i / K, k = i - n * K;
    float w = W[i];
    u16 hi = f32_bf16_rne(w);
    u16 lo = f32_bf16_rne(w - bf16_f32(hi));
    W2[(size_t)n * (2 * K) + k] = hi;
    W2[(size_t)n * (2 * K) + K + k] = lo;
}

// ---------------- aggregation (fp32 gather) + split-bf16 output ----------------

template <int V> struct VecT;
template <> struct VecT<2> { using T = float2; };
template <> struct VecT<4> { using T = float4; };

template <int C>
__global__ __launch_bounds__(256) void k_aggregate_split(
    const float* __restrict__ x,       // [>=NNODES][C] f32
    const int* __restrict__ offs,
    const int* __restrict__ csr_src,
    const float* __restrict__ csr_w,
    const float* __restrict__ dinv,
    u16* __restrict__ out2,            // [PADM][2C] bf16 [hi(C)|lo(C)]
    int nvalid, int padm)
{
    constexpr int V = C / 64;
    using VT = typename VecT<V>::T;
    int wave = threadIdx.x >> 6;
    int lane = threadIdx.x & 63;
    int node = blockIdx.x * 4 + wave;
    if (node >= padm) return;

    float acc[V];
#pragma unroll
    for (int v = 0; v < V; ++v) acc[v] = 0.f;

    if (node < nvalid) {
        float di = dinv[node];
        float w0 = di * di;
        VT xv = *(const VT*)(x + (size_t)node * C + lane * V);
        const float* xp = (const float*)&xv;
#pragma unroll
        for (int v = 0; v < V; ++v) acc[v] = w0 * xp[v];
        int j0 = offs[node], j1 = offs[node + 1];
        for (int j = j0; j < j1; ++j) {
            int s = csr_src[j];
            float w = csr_w[j];
            VT sv = *(const VT*)(x + (size_t)s * C + lane * V);
            const float* sp = (const float*)&sv;
#pragma unroll
            for (int v = 0; v < V; ++v) acc[v] = fmaf(w, sp[v], acc[v]);
        }
    }

    u16 hi[V], lo[V];
#pragma unroll
    for (int v = 0; v < V; ++v) {
        hi[v] = f32_bf16_rne(acc[v]);
        lo[v] = f32_bf16_rne(acc[v] - bf16_f32(hi[v]));
    }
    u16* po = out2 + (size_t)node * (2 * C) + lane * V;
    if (V == 2) {
        u32 hw = (u32)hi[0] | ((u32)hi[1] << 16);
        u32 lw = (u32)lo[0] | ((u32)lo[1] << 16);
        *(u32*)po = hw;
        *(u32*)(po + C) = lw;
    } else {
        u64 hw = (u64)hi[0] | ((u64)hi[1] << 16) | ((u64)hi[2] << 32) | ((u64)hi[3] << 48);
        u64 lw = (u64)lo[0] | ((u64)lo[1] << 16) | ((u64)lo[2] << 32) | ((u64)lo[3] << 48);
        *(u64*)po = hw;
        *(u64*)(po + C) = lw;
    }
}

// ---------------- MFMA GEMM over split-bf16 operands ----------------
// A2 [M][2K] bf16 [hi|lo], W2 [N][2K] bf16 [hi|lo]
// C = A*W^T (logical fp32 GEMM) via Ah*Bh + Al*Bh + Ah*Bl per 32-k step.
// EPI: 0 = f32 + relu, all rows; 1 = split-bf16 + relu -> Cs[M][2N]; 2 = f32, row<Mvalid

template <int EPI>
__global__ __launch_bounds__(256, 3) void k_mfma_gemm(
    const u16* __restrict__ A2,
    const u16* __restrict__ W2,
    const float* __restrict__ bias,
    float* __restrict__ Cf,
    u16* __restrict__ Cs,
    int N, int K, int Mvalid, int nby)
{
    __shared__ u16 At[128 * 64];   // [row][ hi32 | lo32 ]  (128B rows, XOR-swizzled)
    __shared__ u16 Bt[128 * 64];

    const int id = blockIdx.x;
    const int by = id % nby;
    const int bx = id / nby;
    const int bm0 = bx * 128;
    const int bn0 = by * 128;
    const int tid = threadIdx.x;
    const int lane = tid & 63;
    const int w = tid >> 6, wr = w >> 1, wc = w & 1;
    const int g = lane >> 4, rl = lane & 15;
    const int K2 = 2 * K;

    f32x4 acc[4][4];
#pragma unroll
    for (int i = 0; i < 4; ++i)
#pragma unroll
        for (int j = 0; j < 4; ++j) {
            acc[i][j][0] = 0.f; acc[i][j][1] = 0.f; acc[i][j][2] = 0.f; acc[i][j][3] = 0.f;
        }

    // staging mapping: linear LDS dest, inverse-swizzled global source (guide rule 21)
    size_t aoff[4], boff[4];
    int ldsb[4];
#pragma unroll
    for (int r = 0; r < 4; ++r) {
        int a = r * 4096 + tid * 16;        // byte in 16KB tile
        int row = a >> 7;                   // 128B per row
        int c = a & 127;
        int cs = c ^ ((row & 7) << 4);      // logical byte col
        int ce = (cs < 64) ? (cs >> 1) : (K + ((cs - 64) >> 1));  // elem col (hi/lo block)
        aoff[r] = (size_t)(bm0 + row) * K2 + ce;
        boff[r] = (size_t)(bn0 + row) * K2 + ce;
        ldsb[r] = a;
    }

    for (int k0 = 0; k0 < K; k0 += 32) {
#pragma unroll
        for (int r = 0; r < 4; ++r) {
            __builtin_amdgcn_global_load_lds(
                (const GAS void*)(A2 + aoff[r] + k0),
                (LAS void*)((char*)At + ldsb[r]), 16, 0, 0);
            __builtin_amdgcn_global_load_lds(
                (const GAS void*)(W2 + boff[r] + k0),
                (LAS void*)((char*)Bt + ldsb[r]), 16, 0, 0);
        }
        __syncthreads();   // compiler drains vmcnt(0) here

        bf16x8 ah[4], al[4];
#pragma unroll
        for (int m = 0; m < 4; ++m) {
            int row = wr * 64 + m * 16 + rl;
            int sw = (row & 7) << 4;
            const char* base = (const char*)At + row * 128;
            ah[m] = *(const bf16x8*)(base + ((g * 16) ^ sw));
            al[m] = *(const bf16x8*)(base + ((64 + g * 16) ^ sw));
        }
#pragma unroll
        for (int n = 0; n < 4; ++n) {
            int row = wc * 64 + n * 16 + rl;
            int sw = (row & 7) << 4;
            const char* base = (const char*)Bt + row * 128;
            bf16x8 bh = *(const bf16x8*)(base + ((g * 16) ^ sw));
            bf16x8 bl = *(const bf16x8*)(base + ((64 + g * 16) ^ sw));
#pragma unroll
            for (int m = 0; m < 4; ++m) {
                acc[m][n] = __builtin_amdgcn_mfma_f32_16x16x32_bf16(ah[m], bh, acc[m][n], 0, 0, 0);
                acc[m][n] = __builtin_amdgcn_mfma_f32_16x16x32_bf16(al[m], bh, acc[m][n], 0, 0, 0);
                acc[m][n] = __builtin_amdgcn_mfma_f32_16x16x32_bf16(ah[m], bl, acc[m][n], 0, 0, 0);
            }
        }
        __syncthreads();
    }

    // epilogue: C/D layout col = lane&15, row = (lane>>4)*4 + reg   [m89-verified]
#pragma unroll
    for (int n = 0; n < 4; ++n) {
        int col = bn0 + wc * 64 + n * 16 + rl;
        float bv = bias[col];
#pragma unroll
        for (int m = 0; m < 4; ++m) {
            int row0 = bm0 + wr * 64 + m * 16 + g * 4;
#pragma unroll
            for (int q = 0; q < 4; ++q) {
                int row = row0 + q;
                float v = acc[m][n][q] + bv;
                if (EPI == 0) {
                    Cf[(size_t)row * N + col] = fmaxf(v, 0.f);
                } else if (EPI == 1) {
                    float rv = fmaxf(v, 0.f);
                    u16 hi = f32_bf16_rne(rv);
                    u16 lo = f32_bf16_rne(rv - bf16_f32(hi));
                    Cs[(size_t)row * (2 * N) + col] = hi;
                    Cs[(size_t)row * (2 * N) + N + col] = lo;
                } else {
                    if (row < Mvalid) Cf[(size_t)row * N + col] = v;
                }
            }
        }
    }
}

// ---------------- launch ----------------

static inline size_t align_up(size_t x, size_t a) { return (x + a - 1) & ~(a - 1); }

extern "C" void kernel_launch(void* const* d_in, const int* in_sizes, int n_in,
                              void* d_out, int out_size, void* d_ws, size_t ws_size,
                              hipStream_t stream) {
    const int*   edge_index = (const int*)d_in[0];    // [2][E]
    const float* node = (const float*)d_in[1];        // [NNODES][128]
    const float* W1 = (const float*)d_in[2];
    const float* b1 = (const float*)d_in[3];
    const float* W2 = (const float*)d_in[4];
    const float* b2 = (const float*)d_in[5];
    const float* W3 = (const float*)d_in[6];
    const float* b3 = (const float*)d_in[7];
    const float* Wfc = (const float*)d_in[8];
    const float* bfc = (const float*)d_in[9];
    float* out = (float*)d_out;

    const int E = in_sizes[0] / 2;   // 400000
    const int NV = NNODES;
    const int P = PADM;

    // workspace layout
    char* ws = (char*)d_ws;
    size_t off = 0;
    int* cnt = (int*)(ws + off);          off = align_up(off + (size_t)NV * 4, 1024);
    int* offs = (int*)(ws + off);         off = align_up(off + (size_t)(NV + 1) * 4, 1024);
    int* cursor = (int*)(ws + off);       off = align_up(off + (size_t)NV * 4, 1024);
    float* dinv = (float*)(ws + off);     off = align_up(off + (size_t)NV * 4, 1024);
    int* csr_src = (int*)(ws + off);      off = align_up(off + (size_t)E * 4, 1024);
    float* csr_w = (float*)(ws + off);    off = align_up(off + (size_t)E * 4, 1024);
    u16* W1s = (u16*)(ws + off);          off = align_up(off + (size_t)128 * 256 * 2, 1024);
    u16* W2s = (u16*)(ws + off);          off = align_up(off + (size_t)256 * 256 * 2, 1024);
    u16* W3s = (u16*)(ws + off);          off = align_up(off + (size_t)512 * 512 * 2, 1024);
    u16* Wfcs = (u16*)(ws + off);         off = align_up(off + (size_t)1024 * 1024 * 2, 1024);
    u16* A1s = (u16*)(ws + off);          off = align_up(off + (size_t)P * 256 * 2, 1024);
    u16* A3s = (u16*)(ws + off);          off = align_up(off + (size_t)P * 512 * 2, 1024);
    u16* A4s = (u16*)(ws + off);          off = align_up(off + (size_t)P * 1024 * 2, 1024);
    float* xbuf1 = (float*)(ws + off);    off = align_up(off + (size_t)P * 128 * 4, 1024);
    float* xbuf2 = (float*)(ws + off);    off = align_up(off + (size_t)P * 256 * 4, 1024);

    const int* src = edge_index;
    const int* dst = edge_index + E;

    // weight splits (independent of CSR)
    k_splitW<<<(128 * 128 + 255) / 256, 256, 0, stream>>>(W1, W1s, 128 * 128, 128);
    k_splitW<<<(256 * 128 + 255) / 256, 256, 0, stream>>>(W2, W2s, 256 * 128, 128);
    k_splitW<<<(512 * 256 + 255) / 256, 256, 0, stream>>>(W3, W3s, 512 * 256, 256);
    k_splitW<<<(1024 * 512 + 255) / 256, 256, 0, stream>>>(Wfc, Wfcs, 1024 * 512, 512);

    // CSR build
    k_zero_cnt<<<(NV + 255) / 256, 256, 0, stream>>>(cnt, NV);
    k_count<<<(E + 255) / 256, 256, 0, stream>>>(dst, E, cnt);
    k_dinv<<<(NV + 255) / 256, 256, 0, stream>>>(cnt, dinv, NV);
    k_scan<<<1, 1024, 0, stream>>>(cnt, NV, offs, cursor);
    k_fill<<<(E + 255) / 256, 256, 0, stream>>>(src, dst, E, cursor, dinv, csr_src, csr_w);

    dim3 blk(256);
    int aggGrid = P / 4;
    const int nbx = P / 128;   // 391

    // layer 1
    k_aggregate_split<128><<<aggGrid, blk, 0, stream>>>(node, offs, csr_src, csr_w, dinv, A1s, NV, P);
    k_mfma_gemm<0><<<nbx * 1, blk, 0, stream>>>(A1s, W1s, b1, xbuf1, nullptr, 128, 128, P, 1);

    // layer 2
    k_aggregate_split<128><<<aggGrid, blk, 0, stream>>>(xbuf1, offs, csr_src, csr_w, dinv, A1s, NV, P);
    k_mfma_gemm<0><<<nbx * 2, blk, 0, stream>>>(A1s, W2s, b2, xbuf2, nullptr, 256, 128, P, 2);

    // layer 3 (epilogue writes split-bf16 directly for FC input)
    k_aggregate_split<256><<<aggGrid, blk, 0, stream>>>(xbuf2, offs, csr_src, csr_w, dinv, A3s, NV, P);
    k_mfma_gemm<1><<<nbx * 4, blk, 0, stream>>>(A3s, W3s, b3, nullptr, A4s, 512, 256, P, 4);

    // FC
    k_mfma_gemm<2><<<nbx * 8, blk, 0, stream>>>(A4s, Wfcs, bfc, out, nullptr, 1024, 512, NV, 8);
}

// Round 3
// 600.167 us; speedup vs baseline: 2.0207x; 1.1049x over previous
//
#include <hip/hip_runtime.h>
#include <hip/hip_bf16.h>

typedef unsigned short u16;
typedef unsigned int   u32;
typedef unsigned long long u64;
typedef __attribute__((ext_vector_type(8))) short bf16x8;
typedef __attribute__((ext_vector_type(4))) float f32x4;

#define NNODES 50000
#define PADM   50048          // 128 * 391

#define GAS __attribute__((address_space(1)))
#define LAS __attribute__((address_space(3)))

__device__ __forceinline__ u16 f32_bf16_rne(float x) {
    u32 u = __float_as_uint(x);
    return (u16)((u + 0x7fffu + ((u >> 16) & 1u)) >> 16);
}
__device__ __forceinline__ float bf16_f32(u16 h) {
    return __uint_as_float(((u32)h) << 16);
}

// ---------------- CSR build ----------------

__global__ void k_zero_cnt(int* __restrict__ cnt, int n) {
    int i = blockIdx.x * 256 + threadIdx.x;
    if (i < n) cnt[i] = 0;
}

__global__ void k_count(const int* __restrict__ dst, int E, int* __restrict__ cnt) {
    int e = blockIdx.x * 256 + threadIdx.x;
    if (e < E) atomicAdd(&cnt[dst[e]], 1);
}

__global__ void k_dinv(const int* __restrict__ cnt, float* __restrict__ dinv, int n) {
    int i = blockIdx.x * 256 + threadIdx.x;
    if (i < n) dinv[i] = rsqrtf((float)(cnt[i] + 1));   // +1 self loop
}

__global__ __launch_bounds__(1024) void k_scan(const int* __restrict__ cnt, int n,
                                               int* __restrict__ offs, int* __restrict__ cursor) {
    __shared__ int sums[1024];
    int t = threadIdx.x;
    int per = (n + 1023) / 1024;
    int start = t * per;
    int end = start + per; if (end > n) end = n;
    int s = 0;
    for (int i = start; i < end; ++i) s += cnt[i];
    sums[t] = s;
    __syncthreads();
    for (int d = 1; d < 1024; d <<= 1) {
        int v = (t >= d) ? sums[t - d] : 0;
        __syncthreads();
        sums[t] += v;
        __syncthreads();
    }
    int base = (t == 0) ? 0 : sums[t - 1];
    for (int i = start; i < end; ++i) {
        offs[i] = base; cursor[i] = base;
        base += cnt[i];
    }
    if (t == 1023) offs[n] = sums[1023];
}

__global__ void k_fill(const int* __restrict__ src, const int* __restrict__ dst, int E,
                       int* __restrict__ cursor, const float* __restrict__ dinv,
                       int* __restrict__ csr_src, float* __restrict__ csr_w) {
    int e = blockIdx.x * 256 + threadIdx.x;
    if (e < E) {
        int s = src[e], d = dst[e];
        int slot = atomicAdd(&cursor[d], 1);
        csr_src[slot] = s;
        csr_w[slot] = dinv[s] * dinv[d];
    }
}

// ---------------- weight split: W[N][K] f32 -> [N][2K] bf16 [hi|lo] ----------------

__global__ void k_splitW(const float* __restrict__ W, u16* __restrict__ W2, int total, int K) {
    int i = blockIdx.x * 256 + threadIdx.x;
    if (i >= total) return;
    int n = i / K, k = i - n * K;
    float w = W[i];
    u16 hi = f32_bf16_rne(w);
    u16 lo = f32_bf16_rne(w - bf16_f32(hi));
    W2[(size_t)n * (2 * K) + k] = hi;
    W2[(size_t)n * (2 * K) + K + k] = lo;
}

// ---------------- aggregation (fp32 gather, 4-wide MLP) + split-bf16 output ----------------

template <int V> struct VecT;
template <> struct VecT<2> { using T = float2; };
template <> struct VecT<4> { using T = float4; };

template <int C>
__global__ __launch_bounds__(256) void k_aggregate_split(
    const float* __restrict__ x,       // [>=NNODES][C] f32
    const int* __restrict__ offs,
    const int* __restrict__ csr_src,
    const float* __restrict__ csr_w,
    const float* __restrict__ dinv,
    u16* __restrict__ out2,            // [PADM][2C] bf16 [hi(C)|lo(C)]
    int nvalid, int padm)
{
    constexpr int V = C / 64;
    using VT = typename VecT<V>::T;
    int wave = threadIdx.x >> 6;
    int lane = threadIdx.x & 63;
    int node = blockIdx.x * 4 + wave;
    if (node >= padm) return;

    float acc[V];
#pragma unroll
    for (int v = 0; v < V; ++v) acc[v] = 0.f;

    if (node < nvalid) {
        float di = dinv[node];
        float ws = di * di;
        VT xv = *(const VT*)(x + (size_t)node * C + lane * V);
        const float* xp = (const float*)&xv;
#pragma unroll
        for (int v = 0; v < V; ++v) acc[v] = ws * xp[v];

        int j0 = offs[node], j1 = offs[node + 1];
        int j = j0;
        // 4-wide: 4 independent row gathers in flight per wave
        for (; j + 4 <= j1; j += 4) {
            int s0 = csr_src[j],     s1 = csr_src[j + 1];
            int s2 = csr_src[j + 2], s3 = csr_src[j + 3];
            float w0 = csr_w[j],     w1 = csr_w[j + 1];
            float w2 = csr_w[j + 2], w3 = csr_w[j + 3];
            VT r0 = *(const VT*)(x + (size_t)s0 * C + lane * V);
            VT r1 = *(const VT*)(x + (size_t)s1 * C + lane * V);
            VT r2 = *(const VT*)(x + (size_t)s2 * C + lane * V);
            VT r3 = *(const VT*)(x + (size_t)s3 * C + lane * V);
            const float* p0 = (const float*)&r0;
            const float* p1 = (const float*)&r1;
            const float* p2 = (const float*)&r2;
            const float* p3 = (const float*)&r3;
#pragma unroll
            for (int v = 0; v < V; ++v) {
                acc[v] = fmaf(w0, p0[v], acc[v]);
                acc[v] = fmaf(w1, p1[v], acc[v]);
                acc[v] = fmaf(w2, p2[v], acc[v]);
                acc[v] = fmaf(w3, p3[v], acc[v]);
            }
        }
        // 2-wide tail
        for (; j + 2 <= j1; j += 2) {
            int s0 = csr_src[j], s1 = csr_src[j + 1];
            float w0 = csr_w[j], w1 = csr_w[j + 1];
            VT r0 = *(const VT*)(x + (size_t)s0 * C + lane * V);
            VT r1 = *(const VT*)(x + (size_t)s1 * C + lane * V);
            const float* p0 = (const float*)&r0;
            const float* p1 = (const float*)&r1;
#pragma unroll
            for (int v = 0; v < V; ++v) {
                acc[v] = fmaf(w0, p0[v], acc[v]);
                acc[v] = fmaf(w1, p1[v], acc[v]);
            }
        }
        for (; j < j1; ++j) {
            int s0 = csr_src[j];
            float w0 = csr_w[j];
            VT r0 = *(const VT*)(x + (size_t)s0 * C + lane * V);
            const float* p0 = (const float*)&r0;
#pragma unroll
            for (int v = 0; v < V; ++v) acc[v] = fmaf(w0, p0[v], acc[v]);
        }
    }

    u16 hi[V], lo[V];
#pragma unroll
    for (int v = 0; v < V; ++v) {
        hi[v] = f32_bf16_rne(acc[v]);
        lo[v] = f32_bf16_rne(acc[v] - bf16_f32(hi[v]));
    }
    u16* po = out2 + (size_t)node * (2 * C) + lane * V;
    if (V == 2) {
        u32 hw = (u32)hi[0] | ((u32)hi[1] << 16);
        u32 lw = (u32)lo[0] | ((u32)lo[1] << 16);
        *(u32*)po = hw;
        *(u32*)(po + C) = lw;
    } else {
        u64 hw = (u64)hi[0] | ((u64)hi[1] << 16) | ((u64)hi[2] << 32) | ((u64)hi[3] << 48);
        u64 lw = (u64)lo[0] | ((u64)lo[1] << 16) | ((u64)lo[2] << 32) | ((u64)lo[3] << 48);
        *(u64*)po = hw;
        *(u64*)(po + C) = lw;
    }
}

// ---------------- MFMA GEMM over split-bf16 operands ----------------
// A2 [M][2K] bf16 [hi|lo], W2 [N][2K] bf16 [hi|lo]
// C = A*W^T (logical fp32 GEMM) via Ah*Bh + Al*Bh + Ah*Bl per 32-k step.
// EPI: 0 = f32 + relu, all rows; 1 = split-bf16 + relu -> Cs[M][2N]; 2 = f32, row<Mvalid

template <int EPI>
__global__ __launch_bounds__(256, 4) void k_mfma_gemm(
    const u16* __restrict__ A2,
    const u16* __restrict__ W2,
    const float* __restrict__ bias,
    float* __restrict__ Cf,
    u16* __restrict__ Cs,
    int N, int K, int Mvalid, int nby)
{
    __shared__ u16 At[128 * 64];   // [row][ hi32 | lo32 ]  (128B rows, XOR-swizzled)
    __shared__ u16 Bt[128 * 64];

    // T1: bijective XCD swizzle (m204) — blocks on one XCD cover contiguous
    // logical ids; with `by` fastest they share A-panels in that XCD's L2.
    const int nwg = gridDim.x;
    const int orig = blockIdx.x;
    const int q8 = nwg >> 3, r8 = nwg & 7;
    const int xcd = orig & 7, slot = orig >> 3;
    const int L = (xcd < r8 ? xcd * (q8 + 1) : r8 * (q8 + 1) + (xcd - r8) * q8) + slot;
    const int by = L % nby;
    const int bx = L / nby;
    const int bm0 = bx * 128;
    const int bn0 = by * 128;
    const int tid = threadIdx.x;
    const int lane = tid & 63;
    const int w = tid >> 6, wr = w >> 1, wc = w & 1;
    const int g = lane >> 4, rl = lane & 15;
    const int K2 = 2 * K;

    f32x4 acc[4][4];
#pragma unroll
    for (int i = 0; i < 4; ++i)
#pragma unroll
        for (int j = 0; j < 4; ++j) {
            acc[i][j][0] = 0.f; acc[i][j][1] = 0.f; acc[i][j][2] = 0.f; acc[i][j][3] = 0.f;
        }

    // staging mapping: linear LDS dest, inverse-swizzled global source (guide rule 21)
    size_t aoff[4], boff[4];
    int ldsb[4];
#pragma unroll
    for (int r = 0; r < 4; ++r) {
        int a = r * 4096 + tid * 16;        // byte in 16KB tile
        int row = a >> 7;                   // 128B per row
        int c = a & 127;
        int cs = c ^ ((row & 7) << 4);      // logical byte col
        int ce = (cs < 64) ? (cs >> 1) : (K + ((cs - 64) >> 1));  // elem col (hi/lo block)
        aoff[r] = (size_t)(bm0 + row) * K2 + ce;
        boff[r] = (size_t)(bn0 + row) * K2 + ce;
        ldsb[r] = a;
    }

    for (int k0 = 0; k0 < K; k0 += 32) {
#pragma unroll
        for (int r = 0; r < 4; ++r) {
            __builtin_amdgcn_global_load_lds(
                (const GAS void*)(A2 + aoff[r] + k0),
                (LAS void*)((char*)At + ldsb[r]), 16, 0, 0);
            __builtin_amdgcn_global_load_lds(
                (const GAS void*)(W2 + boff[r] + k0),
                (LAS void*)((char*)Bt + ldsb[r]), 16, 0, 0);
        }
        __syncthreads();   // compiler drains vmcnt(0) here

        bf16x8 ah[4], al[4];
#pragma unroll
        for (int m = 0; m < 4; ++m) {
            int row = wr * 64 + m * 16 + rl;
            int sw = (row & 7) << 4;
            const char* base = (const char*)At + row * 128;
            ah[m] = *(const bf16x8*)(base + ((g * 16) ^ sw));
            al[m] = *(const bf16x8*)(base + ((64 + g * 16) ^ sw));
        }
#pragma unroll
        for (int n = 0; n < 4; ++n) {
            int row = wc * 64 + n * 16 + rl;
            int sw = (row & 7) << 4;
            const char* base = (const char*)Bt + row * 128;
            bf16x8 bh = *(const bf16x8*)(base + ((g * 16) ^ sw));
            bf16x8 bl = *(const bf16x8*)(base + ((64 + g * 16) ^ sw));
#pragma unroll
            for (int m = 0; m < 4; ++m) {
                acc[m][n] = __builtin_amdgcn_mfma_f32_16x16x32_bf16(ah[m], bh, acc[m][n], 0, 0, 0);
                acc[m][n] = __builtin_amdgcn_mfma_f32_16x16x32_bf16(al[m], bh, acc[m][n], 0, 0, 0);
                acc[m][n] = __builtin_amdgcn_mfma_f32_16x16x32_bf16(ah[m], bl, acc[m][n], 0, 0, 0);
            }
        }
        __syncthreads();
    }

    // epilogue: C/D layout col = lane&15, row = (lane>>4)*4 + reg   [m89-verified]
#pragma unroll
    for (int n = 0; n < 4; ++n) {
        int col = bn0 + wc * 64 + n * 16 + rl;
        float bv = bias[col];
#pragma unroll
        for (int m = 0; m < 4; ++m) {
            int row0 = bm0 + wr * 64 + m * 16 + g * 4;
#pragma unroll
            for (int q = 0; q < 4; ++q) {
                int row = row0 + q;
                float v = acc[m][n][q] + bv;
                if (EPI == 0) {
                    Cf[(size_t)row * N + col] = fmaxf(v, 0.f);
                } else if (EPI == 1) {
                    float rv = fmaxf(v, 0.f);
                    u16 hi = f32_bf16_rne(rv);
                    u16 lo = f32_bf16_rne(rv - bf16_f32(hi));
                    Cs[(size_t)row * (2 * N) + col] = hi;
                    Cs[(size_t)row * (2 * N) + N + col] = lo;
                } else {
                    if (row < Mvalid) Cf[(size_t)row * N + col] = v;
                }
            }
        }
    }
}

// ---------------- launch ----------------

static inline size_t align_up(size_t x, size_t a) { return (x + a - 1) & ~(a - 1); }

extern "C" void kernel_launch(void* const* d_in, const int* in_sizes, int n_in,
                              void* d_out, int out_size, void* d_ws, size_t ws_size,
                              hipStream_t stream) {
    const int*   edge_index = (const int*)d_in[0];    // [2][E]
    const float* node = (const float*)d_in[1];        // [NNODES][128]
    const float* W1 = (const float*)d_in[2];
    const float* b1 = (const float*)d_in[3];
    const float* W2 = (const float*)d_in[4];
    const float* b2 = (const float*)d_in[5];
    const float* W3 = (const float*)d_in[6];
    const float* b3 = (const float*)d_in[7];
    const float* Wfc = (const float*)d_in[8];
    const float* bfc = (const float*)d_in[9];
    float* out = (float*)d_out;

    const int E = in_sizes[0] / 2;   // 400000
    const int NV = NNODES;
    const int P = PADM;

    // workspace layout
    char* ws = (char*)d_ws;
    size_t off = 0;
    int* cnt = (int*)(ws + off);          off = align_up(off + (size_t)NV * 4, 1024);
    int* offs = (int*)(ws + off);         off = align_up(off + (size_t)(NV + 1) * 4, 1024);
    int* cursor = (int*)(ws + off);       off = align_up(off + (size_t)NV * 4, 1024);
    float* dinv = (float*)(ws + off);     off = align_up(off + (size_t)NV * 4, 1024);
    int* csr_src = (int*)(ws + off);      off = align_up(off + (size_t)E * 4, 1024);
    float* csr_w = (float*)(ws + off);    off = align_up(off + (size_t)E * 4, 1024);
    u16* W1s = (u16*)(ws + off);          off = align_up(off + (size_t)128 * 256 * 2, 1024);
    u16* W2s = (u16*)(ws + off);          off = align_up(off + (size_t)256 * 256 * 2, 1024);
    u16* W3s = (u16*)(ws + off);          off = align_up(off + (size_t)512 * 512 * 2, 1024);
    u16* Wfcs = (u16*)(ws + off);         off = align_up(off + (size_t)1024 * 1024 * 2, 1024);
    u16* A1s = (u16*)(ws + off);          off = align_up(off + (size_t)P * 256 * 2, 1024);
    u16* A3s = (u16*)(ws + off);          off = align_up(off + (size_t)P * 512 * 2, 1024);
    u16* A4s = (u16*)(ws + off);          off = align_up(off + (size_t)P * 1024 * 2, 1024);
    float* xbuf1 = (float*)(ws + off);    off = align_up(off + (size_t)P * 128 * 4, 1024);
    float* xbuf2 = (float*)(ws + off);    off = align_up(off + (size_t)P * 256 * 4, 1024);

    const int* src = edge_index;
    const int* dst = edge_index + E;

    // weight splits (independent of CSR)
    k_splitW<<<(128 * 128 + 255) / 256, 256, 0, stream>>>(W1, W1s, 128 * 128, 128);
    k_splitW<<<(256 * 128 + 255) / 256, 256, 0, stream>>>(W2, W2s, 256 * 128, 128);
    k_splitW<<<(512 * 256 + 255) / 256, 256, 0, stream>>>(W3, W3s, 512 * 256, 256);
    k_splitW<<<(1024 * 512 + 255) / 256, 256, 0, stream>>>(Wfc, Wfcs, 1024 * 512, 512);

    // CSR build
    k_zero_cnt<<<(NV + 255) / 256, 256, 0, stream>>>(cnt, NV);
    k_count<<<(E + 255) / 256, 256, 0, stream>>>(dst, E, cnt);
    k_dinv<<<(NV + 255) / 256, 256, 0, stream>>>(cnt, dinv, NV);
    k_scan<<<1, 1024, 0, stream>>>(cnt, NV, offs, cursor);
    k_fill<<<(E + 255) / 256, 256, 0, stream>>>(src, dst, E, cursor, dinv, csr_src, csr_w);

    dim3 blk(256);
    int aggGrid = P / 4;
    const int nbx = P / 128;   // 391

    // layer 1
    k_aggregate_split<128><<<aggGrid, blk, 0, stream>>>(node, offs, csr_src, csr_w, dinv, A1s, NV, P);
    k_mfma_gemm<0><<<nbx * 1, blk, 0, stream>>>(A1s, W1s, b1, xbuf1, nullptr, 128, 128, P, 1);

    // layer 2
    k_aggregate_split<128><<<aggGrid, blk, 0, stream>>>(xbuf1, offs, csr_src, csr_w, dinv, A1s, NV, P);
    k_mfma_gemm<0><<<nbx * 2, blk, 0, stream>>>(A1s, W2s, b2, xbuf2, nullptr, 256, 128, P, 2);

    // layer 3 (epilogue writes split-bf16 directly for FC input)
    k_aggregate_split<256><<<aggGrid, blk, 0, stream>>>(xbuf2, offs, csr_src, csr_w, dinv, A3s, NV, P);
    k_mfma_gemm<1><<<nbx * 4, blk, 0, stream>>>(A3s, W3s, b3, nullptr, A4s, 512, 256, P, 4);

    // FC
    k_mfma_gemm<2><<<nbx * 8, blk, 0, stream>>>(A4s, Wfcs, bfc, out, nullptr, 1024, 512, NV, 8);
}